// Round 5
// baseline (330.002 us; speedup 1.0000x reference)
//
#include <hip/hip_runtime.h>

#define NN 100000
#define NE 1000000
#define SDIM 24     // padded s row: [0..2]=user agg, [3..20]=movie agg, 21..23 pad
#define BSH 9       // bucket shift: 512 cols per bucket
#define BCOLS 512
#define NBUCK 196   // ceil(NN / 512)
#define SBLK 128    // scatter/hist blocks (edge partition)
#define STHR 256

// ---------------------------------------------------------------------------
// K_f: fuse linear chain: M[21][128] = [Wu@W1_top ; Wm@W1_bot],
// b1p = b1 + bu@W1_top + bm@W1_bot. Runs once (~3 us).
// ---------------------------------------------------------------------------
__global__ __launch_bounds__(128) void fuse_kernel(const float* __restrict__ Wu,
                                                   const float* __restrict__ bu,
                                                   const float* __restrict__ Wm,
                                                   const float* __restrict__ bm,
                                                   const float* __restrict__ W1,
                                                   const float* __restrict__ b1,
                                                   float* __restrict__ M,
                                                   float* __restrict__ b1p) {
    const int j = threadIdx.x;
    float w1c[128];
#pragma unroll
    for (int k = 0; k < 128; k++) w1c[k] = W1[k * 128 + j];

#pragma unroll
    for (int m = 0; m < 3; m++) {
        float acc = 0.f;
#pragma unroll
        for (int k = 0; k < 64; k++) acc = fmaf(Wu[m * 64 + k], w1c[k], acc);
        M[m * 128 + j] = acc;
    }
#pragma unroll
    for (int m = 0; m < 18; m++) {
        float acc = 0.f;
#pragma unroll
        for (int k = 0; k < 64; k++) acc = fmaf(Wm[m * 64 + k], w1c[64 + k], acc);
        M[(3 + m) * 128 + j] = acc;
    }
    float bp = b1[j];
#pragma unroll
    for (int k = 0; k < 64; k++) {
        bp = fmaf(bu[k], w1c[k], bp);
        bp = fmaf(bm[k], w1c[64 + k], bp);
    }
    b1p[j] = bp;
}

// ---------------------------------------------------------------------------
// K_a: per-(block,bucket) histogram. Block blk histograms ITS grid-stride
// edge share into LDS, writes H[b*SBLK + blk]. No global atomics.
// ---------------------------------------------------------------------------
__global__ __launch_bounds__(STHR) void bhist_kernel(const int* __restrict__ col,
                                                     int* __restrict__ H) {
    __shared__ int h[NBUCK];
    for (int i = threadIdx.x; i < NBUCK; i += STHR) h[i] = 0;
    __syncthreads();
    for (int e = blockIdx.x * STHR + threadIdx.x; e < NE; e += SBLK * STHR)
        atomicAdd(&h[col[e] >> BSH], 1);
    __syncthreads();
    for (int b = threadIdx.x; b < NBUCK; b += STHR)
        H[b * SBLK + blockIdx.x] = h[b];
}

// ---------------------------------------------------------------------------
// K_b: exclusive scan of H (NBUCK*SBLK = 25088 ints) in one block.
// Order is bucket-major, so H[b*SBLK+blk] becomes the mid-array base of the
// (b,blk) run; H[b*SBLK] is the start of bucket b.
// ---------------------------------------------------------------------------
__global__ __launch_bounds__(1024) void bscan_kernel(int* __restrict__ H) {
    const int TOT = NBUCK * SBLK;          // 25088
    const int PER = 25;                    // 1024*25 >= TOT
    const int t = threadIdx.x;
    const int base = t * PER;
    int v[PER];
    int sum = 0;
#pragma unroll
    for (int i = 0; i < PER; i++) {
        int idx = base + i;
        v[i] = (idx < TOT) ? H[idx] : 0;
        sum += v[i];
    }
    __shared__ int s[1024];
    s[t] = sum;
    __syncthreads();
    for (int off = 1; off < 1024; off <<= 1) {
        int x = (t >= off) ? s[t - off] : 0;
        __syncthreads();
        s[t] += x;
        __syncthreads();
    }
    int run = s[t] - sum;  // exclusive prefix of this thread's chunk
#pragma unroll
    for (int i = 0; i < PER; i++) {
        int idx = base + i;
        if (idx < TOT) H[idx] = run;
        run += v[i];
    }
}

// ---------------------------------------------------------------------------
// K_c: deterministic scatter. Block blk re-reads its edge share and writes
// each edge into its pre-reserved (b,blk) run. Runs are ~320 B contiguous and
// written by one block (one XCD) -> full-line writebacks, no global atomics.
// Payload: x = (col&511) | (row<<9)  (17+9=26 bits), y = ew bits.
// ---------------------------------------------------------------------------
__global__ __launch_bounds__(STHR) void bscatter_kernel(const int* __restrict__ ei,
                                                        const float* __restrict__ ew,
                                                        const int* __restrict__ H,
                                                        int2* __restrict__ mid) {
    __shared__ int rbase[NBUCK];
    __shared__ int rcnt[NBUCK];
    for (int i = threadIdx.x; i < NBUCK; i += STHR) {
        rbase[i] = H[i * SBLK + blockIdx.x];
        rcnt[i] = 0;
    }
    __syncthreads();
    for (int e = blockIdx.x * STHR + threadIdx.x; e < NE; e += SBLK * STHR) {
        const int c = ei[NE + e];
        const int r = ei[e];
        const float w = ew[e];
        const int b = c >> BSH;
        const int pos = rbase[b] + atomicAdd(&rcnt[b], 1);
        mid[pos] = make_int2((c & (BCOLS - 1)) | (r << BSH), __float_as_int(w));
    }
}

// ---------------------------------------------------------------------------
// K_d: per-bucket degree -> dinv. One block per bucket; LDS accumulate from
// the contiguous mid segment; dinv = rsqrt(deg + 1) written coalesced.
// ---------------------------------------------------------------------------
__global__ __launch_bounds__(256) void bdeg_kernel(const int2* __restrict__ mid,
                                                   const int* __restrict__ H,
                                                   float* __restrict__ dinv) {
    __shared__ float dl[BCOLS];
    const int b = blockIdx.x;
    for (int i = threadIdx.x; i < BCOLS; i += 256) dl[i] = 0.f;
    __syncthreads();
    const int start = H[b * SBLK];
    const int end = (b + 1 < NBUCK) ? H[(b + 1) * SBLK] : NE;
    for (int i = start + threadIdx.x; i < end; i += 256) {
        const int2 p = mid[i];
        atomicAdd(&dl[p.x & (BCOLS - 1)], __int_as_float(p.y));
    }
    __syncthreads();
    for (int i = threadIdx.x; i < BCOLS; i += 256) {
        const int c = b * BCOLS + i;
        if (c < NN) dinv[c] = rsqrtf(dl[i] + 1.0f);
    }
}

// ---------------------------------------------------------------------------
// K_e: bucket aggregation. One block (1024 thr) per bucket; 512x21 float LDS
// accumulator (stride 21 coprime with 32 banks). Edge-parallel ds_add_f32;
// self-loop + dc scaling fused; s written coalesced with stride-24 padding.
// ---------------------------------------------------------------------------
#define AT 1024
__global__ __launch_bounds__(AT) void bagg_kernel(const int2* __restrict__ mid,
                                                  const int* __restrict__ H,
                                                  const float* __restrict__ dinv,
                                                  const float* __restrict__ ux,
                                                  const float* __restrict__ mx,
                                                  float* __restrict__ s) {
    __shared__ float sa[BCOLS * 21];  // 43008 B
    const int b = blockIdx.x;
    for (int i = threadIdx.x; i < BCOLS * 21; i += AT) sa[i] = 0.f;
    __syncthreads();

    const int start = H[b * SBLK];
    const int end = (b + 1 < NBUCK) ? H[(b + 1) * SBLK] : NE;
    for (int i = start + threadIdx.x; i < end; i += AT) {
        const int2 p = mid[i];
        const int cl = p.x & (BCOLS - 1);
        const int row = ((unsigned)p.x) >> BSH;
        const float dw = dinv[row] * __int_as_float(p.y);
        float* sb = &sa[cl * 21];
        const float* u = ux + (size_t)row * 3;
        atomicAdd(&sb[0], dw * u[0]);
        atomicAdd(&sb[1], dw * u[1]);
        atomicAdd(&sb[2], dw * u[2]);
        const float2* m2 = (const float2*)(mx + (size_t)row * 18);
#pragma unroll
        for (int k = 0; k < 9; k++) {
            const float2 mv = m2[k];
            atomicAdd(&sb[3 + 2 * k], dw * mv.x);
            atomicAdd(&sb[4 + 2 * k], dw * mv.y);
        }
    }
    __syncthreads();

    // self-loop + final dc scale, in place (threads 0..511 active)
    for (int cl = threadIdx.x; cl < BCOLS; cl += AT) {
        const int c = b * BCOLS + cl;
        if (c >= NN) continue;
        const float dc = dinv[c];
        float* sb = &sa[cl * 21];
        const float* uc = ux + (size_t)c * 3;
        const float* mc = mx + (size_t)c * 18;
        sb[0] = dc * fmaf(dc, uc[0], sb[0]);
        sb[1] = dc * fmaf(dc, uc[1], sb[1]);
        sb[2] = dc * fmaf(dc, uc[2], sb[2]);
#pragma unroll
        for (int k = 0; k < 18; k++) sb[3 + k] = dc * fmaf(dc, mc[k], sb[3 + k]);
    }
    __syncthreads();

    // coalesced stride-24 writeout
    for (int g = threadIdx.x; g < BCOLS * SDIM; g += AT) {
        const int cl = g / SDIM;
        const int k = g - cl * SDIM;
        const int c = b * BCOLS + cl;
        if (c >= NN) continue;
        s[(size_t)c * SDIM + k] = (k < 21) ? sa[cl * 21 + k] : 0.f;
    }
}

// ---------------------------------------------------------------------------
// K_g: fused MLP. One wave per node; lane j holds M[:,j], M[:,j+64].
// out[node] = relu(s.M + b1p) @ W2 + b2.
// ---------------------------------------------------------------------------
__global__ __launch_bounds__(256) void mlp_fused_kernel(const float* __restrict__ s,
                                                        const float* __restrict__ M,
                                                        const float* __restrict__ b1p,
                                                        const float* __restrict__ W2,
                                                        const float* __restrict__ b2,
                                                        float* __restrict__ out) {
    const int lane = threadIdx.x & 63;
    const int wid = (blockIdx.x * blockDim.x + threadIdx.x) >> 6;
    const int nw = (gridDim.x * blockDim.x) >> 6;

    float Ma[21], Mb[21];
#pragma unroll
    for (int m = 0; m < 21; m++) {
        Ma[m] = M[m * 128 + lane];
        Mb[m] = M[m * 128 + 64 + lane];
    }
    const float ba = b1p[lane], bb = b1p[64 + lane];
    const float w2a = W2[lane], w2b = W2[64 + lane];
    const float b2v = b2[0];

    for (int node = wid; node < NN; node += nw) {
        const float4* sp = (const float4*)(s + (size_t)node * SDIM);
        float sv[24];
        ((float4*)sv)[0] = sp[0];
        ((float4*)sv)[1] = sp[1];
        ((float4*)sv)[2] = sp[2];
        ((float4*)sv)[3] = sp[3];
        ((float4*)sv)[4] = sp[4];
        ((float4*)sv)[5] = sp[5];

        float ha = ba, hb = bb;
#pragma unroll
        for (int m = 0; m < 21; m++) {
            ha = fmaf(sv[m], Ma[m], ha);
            hb = fmaf(sv[m], Mb[m], hb);
        }
        float o = fmaf(fmaxf(ha, 0.f), w2a, fmaxf(hb, 0.f) * w2b);
#pragma unroll
        for (int off = 32; off > 0; off >>= 1) o += __shfl_down(o, off);
        if (lane == 0) out[node] = o + b2v;
    }
}

// ===========================================================================
extern "C" void kernel_launch(void* const* d_in, const int* in_sizes, int n_in,
                              void* d_out, int out_size, void* d_ws, size_t ws_size,
                              hipStream_t stream) {
    const float* ux = (const float*)d_in[0];   // user_x  [N,3]
    const float* mx = (const float*)d_in[1];   // movie_x [N,18]
    const int* ei = (const int*)d_in[2];       // edge_index [2,E]
    const float* ew = (const float*)d_in[3];   // edge_attr [E]
    const float* Wu = (const float*)d_in[4];   // [3,64]
    const float* bu = (const float*)d_in[5];   // [64]
    const float* Wm = (const float*)d_in[6];   // [18,64]
    const float* bm = (const float*)d_in[7];   // [64]
    const float* W1 = (const float*)d_in[8];   // [128,128]
    const float* b1 = (const float*)d_in[9];   // [128]
    const float* W2 = (const float*)d_in[10];  // [128,1]
    const float* b2 = (const float*)d_in[11];  // [1]
    float* out = (float*)d_out;

    char* ws = (char*)d_ws;
    float* s    = (float*)ws;                        // NN*24*4 = 9,600,000 B
    float* dinv = (float*)(ws + 9600000);            // 400,000 B
    int*   H    = (int*)(ws + 10000000);             // NBUCK*SBLK*4 = 100,352 B
    float* M    = (float*)(ws + 10100352);           // 10,752 B
    float* b1p  = (float*)(ws + 10111104);           // 512 B
    int2*  mid  = (int2*)(ws + 10111616);            // NE*8 = 8,000,000 B
    // total ~18.1 MB; no memsets needed (every byte used is written first)

    fuse_kernel<<<1, 128, 0, stream>>>(Wu, bu, Wm, bm, W1, b1, M, b1p);
    bhist_kernel<<<SBLK, STHR, 0, stream>>>(ei + NE, H);
    bscan_kernel<<<1, 1024, 0, stream>>>(H);
    bscatter_kernel<<<SBLK, STHR, 0, stream>>>(ei, ew, H, mid);
    bdeg_kernel<<<NBUCK, 256, 0, stream>>>(mid, H, dinv);
    bagg_kernel<<<NBUCK, AT, 0, stream>>>(mid, H, dinv, ux, mx, s);
    mlp_fused_kernel<<<2048, 256, 0, stream>>>(s, M, b1p, W2, b2, out);
}

// Round 6
// 239.474 us; speedup vs baseline: 1.3780x; 1.3780x over previous
//
#include <hip/hip_runtime.h>

#define NN 100000
#define NE 1000000
#define BSH 9       // bucket shift: 512 cols per bucket
#define BCOLS 512
#define NBUCK 196   // ceil(NN / 512)
#define SBLK 128    // scatter/hist blocks (edge partition)
#define STHR 256
#define CAP 8192    // max edges/bucket handled via the sorted path (mean 5102)

// ---------------------------------------------------------------------------
// K_f: fuse the whole linear chain into Mt[128][24]:
//   Mt[k][0..20]  = fused GCN->layer1 matrix column k ( [Wu@W1_top; Wm@W1_bot] )
//   Mt[k][21]     = b1'[k] = b1[k] + bu@W1_top[:,k] + bm@W1_bot[:,k]
//   Mt[k][22]     = W2[k]
// Row-contiguous so the consumer reads each k as wave-uniform scalar loads.
// ---------------------------------------------------------------------------
__global__ __launch_bounds__(128) void fuse_kernel(const float* __restrict__ Wu,
                                                   const float* __restrict__ bu,
                                                   const float* __restrict__ Wm,
                                                   const float* __restrict__ bm,
                                                   const float* __restrict__ W1,
                                                   const float* __restrict__ b1,
                                                   const float* __restrict__ W2,
                                                   float* __restrict__ Mt) {
    const int j = threadIdx.x;
    float w1c[128];
#pragma unroll
    for (int k = 0; k < 128; k++) w1c[k] = W1[k * 128 + j];

    float* row = Mt + j * 24;
#pragma unroll
    for (int m = 0; m < 3; m++) {
        float acc = 0.f;
#pragma unroll
        for (int k = 0; k < 64; k++) acc = fmaf(Wu[m * 64 + k], w1c[k], acc);
        row[m] = acc;
    }
#pragma unroll
    for (int m = 0; m < 18; m++) {
        float acc = 0.f;
#pragma unroll
        for (int k = 0; k < 64; k++) acc = fmaf(Wm[m * 64 + k], w1c[64 + k], acc);
        row[3 + m] = acc;
    }
    float bp = b1[j];
#pragma unroll
    for (int k = 0; k < 64; k++) {
        bp = fmaf(bu[k], w1c[k], bp);
        bp = fmaf(bm[k], w1c[64 + k], bp);
    }
    row[21] = bp;
    row[22] = W2[j];
    row[23] = 0.f;
}

// ---------------------------------------------------------------------------
// K_a: per-(block,bucket) histogram. Block blk histograms ITS grid-stride
// edge share into LDS, writes H[b*SBLK + blk]. No global atomics.
// ---------------------------------------------------------------------------
__global__ __launch_bounds__(STHR) void bhist_kernel(const int* __restrict__ col,
                                                     int* __restrict__ H) {
    __shared__ int h[NBUCK];
    for (int i = threadIdx.x; i < NBUCK; i += STHR) h[i] = 0;
    __syncthreads();
    for (int e = blockIdx.x * STHR + threadIdx.x; e < NE; e += SBLK * STHR)
        atomicAdd(&h[col[e] >> BSH], 1);
    __syncthreads();
    for (int b = threadIdx.x; b < NBUCK; b += STHR)
        H[b * SBLK + blockIdx.x] = h[b];
}

// ---------------------------------------------------------------------------
// K_b: exclusive scan of H (NBUCK*SBLK = 25088 ints) in one block.
// ---------------------------------------------------------------------------
__global__ __launch_bounds__(1024) void bscan_kernel(int* __restrict__ H) {
    const int TOT = NBUCK * SBLK;          // 25088
    const int PER = 25;                    // 1024*25 >= TOT
    const int t = threadIdx.x;
    const int base = t * PER;
    int v[PER];
    int sum = 0;
#pragma unroll
    for (int i = 0; i < PER; i++) {
        int idx = base + i;
        v[i] = (idx < TOT) ? H[idx] : 0;
        sum += v[i];
    }
    __shared__ int s[1024];
    s[t] = sum;
    __syncthreads();
    for (int off = 1; off < 1024; off <<= 1) {
        int x = (t >= off) ? s[t - off] : 0;
        __syncthreads();
        s[t] += x;
        __syncthreads();
    }
    int run = s[t] - sum;
#pragma unroll
    for (int i = 0; i < PER; i++) {
        int idx = base + i;
        if (idx < TOT) H[idx] = run;
        run += v[i];
    }
}

// ---------------------------------------------------------------------------
// K_c: deterministic scatter into per-(bucket,block) runs. No global atomics.
// Payload: x = (col&511) | (row<<9)  (17+9=26 bits), y = ew bits.
// ---------------------------------------------------------------------------
__global__ __launch_bounds__(STHR) void bscatter_kernel(const int* __restrict__ ei,
                                                        const float* __restrict__ ew,
                                                        const int* __restrict__ H,
                                                        int2* __restrict__ mid) {
    __shared__ int rbase[NBUCK];
    __shared__ int rcnt[NBUCK];
    for (int i = threadIdx.x; i < NBUCK; i += STHR) {
        rbase[i] = H[i * SBLK + blockIdx.x];
        rcnt[i] = 0;
    }
    __syncthreads();
    for (int e = blockIdx.x * STHR + threadIdx.x; e < NE; e += SBLK * STHR) {
        const int c = ei[NE + e];
        const int r = ei[e];
        const float w = ew[e];
        const int b = c >> BSH;
        const int pos = rbase[b] + atomicAdd(&rcnt[b], 1);
        mid[pos] = make_int2((c & (BCOLS - 1)) | (r << BSH), __float_as_int(w));
    }
}

// ---------------------------------------------------------------------------
// K_d: per-bucket degree -> dinv. dinv = rsqrt(deg + 1).
// ---------------------------------------------------------------------------
__global__ __launch_bounds__(256) void bdeg_kernel(const int2* __restrict__ mid,
                                                   const int* __restrict__ H,
                                                   float* __restrict__ dinv) {
    __shared__ float dl[BCOLS];
    const int b = blockIdx.x;
    for (int i = threadIdx.x; i < BCOLS; i += 256) dl[i] = 0.f;
    __syncthreads();
    const int start = H[b * SBLK];
    const int end = (b + 1 < NBUCK) ? H[(b + 1) * SBLK] : NE;
    for (int i = start + threadIdx.x; i < end; i += 256) {
        const int2 p = mid[i];
        atomicAdd(&dl[p.x & (BCOLS - 1)], __int_as_float(p.y));
    }
    __syncthreads();
    for (int i = threadIdx.x; i < BCOLS; i += 256) {
        const int c = b * BCOLS + i;
        if (c < NN) dinv[c] = rsqrtf(dl[i] + 1.0f);
    }
}

// ---------------------------------------------------------------------------
// K_e: per-bucket counting-sort (indices only) + col-per-thread register
// aggregation + fused MLP. One block of 512 threads per bucket; thread t owns
// col t. No LDS float accumulation, no s array, no separate MLP kernel.
// ---------------------------------------------------------------------------
__global__ __launch_bounds__(BCOLS) void bagg_mlp_kernel(const int2* __restrict__ mid,
                                                         const int* __restrict__ H,
                                                         const float* __restrict__ dinv,
                                                         const float* __restrict__ ux,
                                                         const float* __restrict__ mx,
                                                         const float* __restrict__ Mt,
                                                         const float* __restrict__ b2,
                                                         float* __restrict__ out) {
    __shared__ unsigned short idx16[CAP];   // 16 KB: permutation only
    __shared__ int cbase[BCOLS + 1];        // exclusive offsets (immutable)
    __shared__ int ccur[BCOLS];             // running counters

    const int b = blockIdx.x;
    const int t = threadIdx.x;              // t == local col
    const int start = H[b * SBLK];
    const int end = (b + 1 < NBUCK) ? H[(b + 1) * SBLK] : NE;
    const int seg = end - start;
    const int segc = seg < CAP ? seg : CAP;

    // phase 1: per-col counts
    ccur[t] = 0;
    __syncthreads();
    for (int i = t; i < segc; i += BCOLS)
        atomicAdd(&ccur[mid[start + i].x & (BCOLS - 1)], 1);
    __syncthreads();

    // phase 2: exclusive scan of 512 counts (Hillis-Steele, 9 steps)
    const int myc = ccur[t];
    cbase[t] = myc;
    __syncthreads();
    for (int off = 1; off < BCOLS; off <<= 1) {
        int x = (t >= off) ? cbase[t - off] : 0;
        __syncthreads();
        cbase[t] += x;
        __syncthreads();
    }
    const int incl = cbase[t];
    __syncthreads();
    cbase[t] = incl - myc;
    ccur[t] = incl - myc;
    if (t == BCOLS - 1) cbase[BCOLS] = incl;
    __syncthreads();

    // phase 3: build permutation
    for (int i = t; i < segc; i += BCOLS) {
        const int cl = mid[start + i].x & (BCOLS - 1);
        const int pos = atomicAdd(&ccur[cl], 1);
        idx16[pos] = (unsigned short)i;
    }
    __syncthreads();

    // phase 4: col-per-thread register aggregation
    float s21[21];
#pragma unroll
    for (int m = 0; m < 21; m++) s21[m] = 0.f;

    const int s0 = cbase[t], s1 = cbase[t + 1];
    for (int i = s0; i < s1; i++) {
        const int2 p = mid[start + idx16[i]];
        const int row = ((unsigned)p.x) >> BSH;
        const float dw = dinv[row] * __int_as_float(p.y);
        const float* u = ux + (size_t)row * 3;
        s21[0] = fmaf(dw, u[0], s21[0]);
        s21[1] = fmaf(dw, u[1], s21[1]);
        s21[2] = fmaf(dw, u[2], s21[2]);
        const float2* m2 = (const float2*)(mx + (size_t)row * 18);
#pragma unroll
        for (int k = 0; k < 9; k++) {
            const float2 mv = m2[k];
            s21[3 + 2 * k] = fmaf(dw, mv.x, s21[3 + 2 * k]);
            s21[4 + 2 * k] = fmaf(dw, mv.y, s21[4 + 2 * k]);
        }
    }

    // phase 4b: overflow edges (seg > CAP; statistically never for this input,
    // kept for correctness — broadcast walk, each thread claims its col)
    for (int i = CAP; i < seg; i++) {
        const int2 p = mid[start + i];
        if ((p.x & (BCOLS - 1)) == t) {
            const int row = ((unsigned)p.x) >> BSH;
            const float dw = dinv[row] * __int_as_float(p.y);
            const float* u = ux + (size_t)row * 3;
            s21[0] = fmaf(dw, u[0], s21[0]);
            s21[1] = fmaf(dw, u[1], s21[1]);
            s21[2] = fmaf(dw, u[2], s21[2]);
            const float* m = mx + (size_t)row * 18;
#pragma unroll
            for (int k = 0; k < 18; k++) s21[3 + k] = fmaf(dw, m[k], s21[3 + k]);
        }
    }

    const int c = b * BCOLS + t;
    if (c < NN) {
        // phase 5: self-loop + dc scaling, in registers
        const float dc = dinv[c];
        const float* uc = ux + (size_t)c * 3;
        const float* mc = mx + (size_t)c * 18;
        s21[0] = dc * fmaf(dc, uc[0], s21[0]);
        s21[1] = dc * fmaf(dc, uc[1], s21[1]);
        s21[2] = dc * fmaf(dc, uc[2], s21[2]);
#pragma unroll
        for (int k = 0; k < 18; k++) s21[3 + k] = dc * fmaf(dc, mc[k], s21[3 + k]);

        // phase 6: fused MLP. Mt rows are wave-uniform -> scalar loads; s in
        // VGPRs. out[c] = sum_k relu(s.Mt[k][0:21] + b1'[k]) * W2[k] + b2.
        float o = 0.f;
#pragma unroll 4
        for (int k = 0; k < 128; k++) {
            const float* r = Mt + k * 24;
            float h = r[21];
#pragma unroll
            for (int m = 0; m < 21; m++) h = fmaf(s21[m], r[m], h);
            o = fmaf(fmaxf(h, 0.f), r[22], o);
        }
        out[c] = o + b2[0];
    }
}

// ===========================================================================
extern "C" void kernel_launch(void* const* d_in, const int* in_sizes, int n_in,
                              void* d_out, int out_size, void* d_ws, size_t ws_size,
                              hipStream_t stream) {
    const float* ux = (const float*)d_in[0];   // user_x  [N,3]
    const float* mx = (const float*)d_in[1];   // movie_x [N,18]
    const int* ei = (const int*)d_in[2];       // edge_index [2,E]
    const float* ew = (const float*)d_in[3];   // edge_attr [E]
    const float* Wu = (const float*)d_in[4];   // [3,64]
    const float* bu = (const float*)d_in[5];   // [64]
    const float* Wm = (const float*)d_in[6];   // [18,64]
    const float* bm = (const float*)d_in[7];   // [64]
    const float* W1 = (const float*)d_in[8];   // [128,128]
    const float* b1 = (const float*)d_in[9];   // [128]
    const float* W2 = (const float*)d_in[10];  // [128,1]
    const float* b2 = (const float*)d_in[11];  // [1]
    float* out = (float*)d_out;

    char* ws = (char*)d_ws;
    float* dinv = (float*)ws;                        // 400,000 B
    int*   H    = (int*)(ws + 400000);               // 25088*4 = 100,352 B
    float* Mt   = (float*)(ws + 500352);             // 128*24*4 = 12,288 B
    int2*  mid  = (int2*)(ws + 512640);              // NE*8 = 8,000,000 B
    // total ~8.5 MB; no memsets needed

    fuse_kernel<<<1, 128, 0, stream>>>(Wu, bu, Wm, bm, W1, b1, W2, Mt);
    bhist_kernel<<<SBLK, STHR, 0, stream>>>(ei + NE, H);
    bscan_kernel<<<1, 1024, 0, stream>>>(H);
    bscatter_kernel<<<SBLK, STHR, 0, stream>>>(ei, ew, H, mid);
    bdeg_kernel<<<NBUCK, 256, 0, stream>>>(mid, H, dinv);
    bagg_mlp_kernel<<<NBUCK, BCOLS, 0, stream>>>(mid, H, dinv, ux, mx, Mt, b2, out);
}